// Round 2
// baseline (217.321 us; speedup 1.0000x reference)
//
#include <hip/hip_runtime.h>
#include <hip/hip_bf16.h>

typedef __attribute__((ext_vector_type(8))) short short8;
typedef __attribute__((ext_vector_type(4))) float f32x4;

#define NTOK   100000
#define H      150
#define KSEG   160        // padded per-matrix K in wb
#define KTOT   640        // 4 * KSEG
#define BM     128        // rows per block
#define NPAD   160        // padded output cols in wb
#define OUTOFF (NTOK * H)

__device__ __forceinline__ unsigned short f2bf(float f) {
    unsigned int u = __builtin_bit_cast(unsigned int, f);
    u = (u + 0x7FFFu + ((u >> 16) & 1u)) >> 16;   // RNE
    return (unsigned short)u;
}

// ---------------------------------------------------------------------------
// Prepass: pack 4x [150,150] fp32 weights into wb[c][k] bf16, c in [0,160),
// k in [0,640) stacked (w_in | w_out | u_in | u_out), zero-padded.
// wb[c][k] = W_seg[k%160][c]  (transposed: B-frag reads are contiguous in k)
// ---------------------------------------------------------------------------
__global__ void prep_w(const float* __restrict__ w_in, const float* __restrict__ w_out,
                       const float* __restrict__ u_in, const float* __restrict__ u_out,
                       unsigned short* __restrict__ wb) {
    int idx = blockIdx.x * 256 + threadIdx.x;
    if (idx >= NPAD * KTOT) return;
    int c = idx / KTOT;
    int k = idx % KTOT;
    int seg = k / KSEG;
    int k2  = k % KSEG;
    float v = 0.0f;
    if (c < H && k2 < H) {
        const float* W = (seg == 0) ? w_in : (seg == 1) ? w_out : (seg == 2) ? u_in : u_out;
        v = W[k2 * H + c];
    }
    wb[idx] = f2bf(v);
}

// ---------------------------------------------------------------------------
// Main fused kernel: NO LDS, NO barriers. Per block: 128 rows x 160 cols.
// 4 waves (2M x 2N); each wave: 64 rows x 80 cols = 4x5 frags of 16x16,
// K-loop 4 segments x 5 steps of 32, fully unrolled.
// A frags loaded direct from global fp32 (convert in-reg), B frags direct
// from packed bf16 weights (L2-resident, 200 KB).
// ---------------------------------------------------------------------------
__global__ __launch_bounds__(256) void lstm_fused(
        const float* __restrict__ s_in, const float* __restrict__ s_out,
        const float* __restrict__ h_in, const float* __restrict__ h_out,
        const float* __restrict__ last_c, const unsigned short* __restrict__ wb,
        float* __restrict__ out) {
    const int t     = threadIdx.x;
    const int lane  = t & 63;
    const int wid   = t >> 6;
    const int waveM = wid >> 1;   // 0..1
    const int waveN = wid & 1;    // 0..1
    const int row0  = blockIdx.x * BM + waveM * 64;  // wave's first row
    const int lrow  = lane & 15;  // fragment row (A) / col (B)
    const int lko   = lane >> 4;  // k-group 0..3 (8 elems each)

    const float* Xseg[4] = {s_in, s_out, h_in, h_out};

    f32x4 acc[4][5];
#pragma unroll
    for (int m = 0; m < 4; m++)
#pragma unroll
        for (int n = 0; n < 5; n++) acc[m][n] = (f32x4){0.f, 0.f, 0.f, 0.f};

    // Per-m clamped row bases for A loads (OOB rows read row NTOK-1, discarded)
    long abase[4];
#pragma unroll
    for (int m = 0; m < 4; m++) {
        int r = row0 + m * 16 + lrow;
        if (r > NTOK - 1) r = NTOK - 1;
        abase[m] = (long)r * H;
    }

    // B-frag column bases (bf16 elem offsets into wb)
    long bbase[5];
#pragma unroll
    for (int n = 0; n < 5; n++)
        bbase[n] = (long)(waveN * 80 + n * 16 + lrow) * KTOT + lko * 8;

#pragma unroll
    for (int seg = 0; seg < 4; seg++) {
        const float* __restrict__ Xp = Xseg[seg];
#pragma unroll
        for (int s5 = 0; s5 < 5; s5++) {
            const int k2b = s5 * 32 + lko * 8;   // per-lane k within segment

            // ---- B frags: direct from L2-resident packed weights ----
            short8 bf[5];
#pragma unroll
            for (int n = 0; n < 5; n++)
                bf[n] = *(const short8*)&wb[bbase[n] + seg * KSEG + s5 * 32];

            // ---- A frags: direct global fp32 -> bf16 in-reg ----
            short8 af[4];
#pragma unroll
            for (int m = 0; m < 4; m++) {
                float xv[8];
                if (s5 < 4) {
                    // k2b+7 <= 127 < 150: always in-row, 8B-aligned float2s
                    const float* p = &Xp[abase[m] + k2b];
#pragma unroll
                    for (int j = 0; j < 8; j += 2) {
                        float2 v = *(const float2*)&p[j];
                        xv[j] = v.x; xv[j + 1] = v.y;
                    }
                } else {
                    // tail step: k2 in [128,160), elements >= 150 are pad -> 0
#pragma unroll
                    for (int j = 0; j < 8; j++) {
                        int k2 = k2b + j;
                        xv[j] = (k2 < H) ? Xp[abase[m] + k2] : 0.f;
                    }
                }
                short8 a8;
#pragma unroll
                for (int j = 0; j < 8; j++) a8[j] = (short)f2bf(xv[j]);
                af[m] = a8;
            }

            // ---- MFMA 4x5 ----
#pragma unroll
            for (int m = 0; m < 4; m++)
#pragma unroll
                for (int n = 0; n < 5; n++)
                    acc[m][n] = __builtin_amdgcn_mfma_f32_16x16x32_bf16(af[m], bf[n], acc[m][n], 0, 0, 0);
        }
    }

    // ---- fused epilogue: g = sigmoid(pre); cell = g*lc + g*g; hid = g*tanh(cell)
#pragma unroll
    for (int m = 0; m < 4; m++) {
#pragma unroll
        for (int r = 0; r < 4; r++) {
            const int row = row0 + m * 16 + lko * 4 + r;
            if (row >= NTOK) continue;
            const long rb = (long)row * H;
#pragma unroll
            for (int n = 0; n < 5; n++) {
                const int col = waveN * 80 + n * 16 + lrow;
                if (col >= H) continue;
                float pre = acc[m][n][r];
                float e   = __expf(-pre);
                float g   = __builtin_amdgcn_rcpf(1.f + e);
                float lc  = last_c[rb + col];
                float cell = g * lc + g * g;
                float e2  = __expf(-2.f * cell);
                float th  = (1.f - e2) * __builtin_amdgcn_rcpf(1.f + e2);
                out[rb + col]          = g * th;
                out[OUTOFF + rb + col] = cell;
            }
        }
    }
}

extern "C" void kernel_launch(void* const* d_in, const int* in_sizes, int n_in,
                              void* d_out, int out_size, void* d_ws, size_t ws_size,
                              hipStream_t stream) {
    const float* s_in   = (const float*)d_in[0];
    const float* s_out  = (const float*)d_in[1];
    const float* h_in   = (const float*)d_in[2];
    const float* h_out  = (const float*)d_in[3];
    const float* last_c = (const float*)d_in[4];
    const float* w_in   = (const float*)d_in[5];
    const float* w_out  = (const float*)d_in[6];
    const float* u_in   = (const float*)d_in[7];
    const float* u_out  = (const float*)d_in[8];

    unsigned short* wb = (unsigned short*)d_ws;   // 160*640*2 = 204800 B
    float* out = (float*)d_out;

    // Prepass: pack/transpose/convert weights
    prep_w<<<(NPAD * KTOT + 255) / 256, 256, 0, stream>>>(w_in, w_out, u_in, u_out, wb);

    // Main fused GEMM + LSTM pointwise (no LDS, no barriers)
    const int nblocks = (NTOK + BM - 1) / BM;  // 782
    lstm_fused<<<nblocks, 256, 0, stream>>>(s_in, s_out, h_in, h_out, last_c, wb, out);
}